// Round 1
// baseline (31891.986 us; speedup 1.0000x reference)
//
#include <hip/hip_runtime.h>

#define WGSIZE 512
#define PTS_PER_BLOCK 256           // 8 waves * 32 points
#define NPTS (512*1024)
#define NBLOCKS (NPTS/PTS_PER_BLOCK) // 2048

typedef __bf16 bf16x8 __attribute__((ext_vector_type(8)));
typedef float f32x16 __attribute__((ext_vector_type(16)));

// LDS weight tile map (1KB per 32x16 bf16 A-tile, lane-ordered)
#define T_W1F 0    // 4 rowtiles x 3 ksteps  (K=48: [x32, z, t, 1, pad])
#define T_W2F 12   // 4 x 9                  (K=144: [h128, 1, pad])
#define T_W3F 48   // 1 x 9
#define T_W1G 57   // 4 x 1                  (K=16: [z, t, 1, pad])
#define T_W2G 61   // 4 x 9
#define T_W3G 97   // 1 x 9
#define LDS_TILES 106
#define LDS_BYTES (LDS_TILES*1024)

__device__ __forceinline__ unsigned pk_bf16(float a, float b){
  unsigned r;
  asm("v_cvt_pk_bf16_f32 %0, %1, %2" : "=v"(r) : "v"(a), "v"(b));
  return r;
}

__device__ __forceinline__ void swap32(unsigned &d, unsigned &s){
  auto r = __builtin_amdgcn_permlane32_swap((int)d, (int)s, false, false);
  d = (unsigned)r[0];
  s = (unsigned)r[1];
}

__device__ __forceinline__ float fast_tanh(float x){
  float e = __expf(2.0f*x);                       // overflow -> inf -> tanh=1 ok
  return 1.0f - 2.0f*__builtin_amdgcn_rcpf(e + 1.0f);
}

__device__ __forceinline__ unsigned short f2bf(float f){ // RNE f32->bf16
  unsigned u = __float_as_uint(f);
  u += 0x7fffu + ((u>>16)&1u);
  return (unsigned short)(u>>16);
}

__device__ __forceinline__ bf16x8 frag_of(const unsigned wv[4]){
  union { uint4 u; bf16x8 b; } x;
  x.u.x = wv[0]; x.u.y = wv[1]; x.u.z = wv[2]; x.u.w = wv[3];
  return x.b;
}

__device__ __forceinline__ bf16x8 ldA(const char* lds, int tile, int lane){
  union { uint4 u; bf16x8 b; } x;
  x.u = *reinterpret_cast<const uint4*>(lds + tile*1024 + lane*16);
  return x.b;
}

__device__ __forceinline__ f32x16 zero16(){
  f32x16 z;
  #pragma unroll
  for (int i=0;i<16;i++) z[i]=0.0f;
  return z;
}

// C-frag (16 f32, rows base..base+31) -> two B-frag ksteps (bf16), via pk+permlane swaps.
__device__ __forceinline__ void cvt2arr(const float* c, unsigned* b0, unsigned* b1){
  {
    unsigned wa = pk_bf16(c[0], c[1]);
    unsigned wb = pk_bf16(c[2], c[3]);
    unsigned wc = pk_bf16(c[4], c[5]);
    unsigned wd = pk_bf16(c[6], c[7]);
    swap32(wa, wc); swap32(wb, wd);
    b0[0]=wa; b0[1]=wb; b0[2]=wc; b0[3]=wd;
  }
  {
    unsigned wa = pk_bf16(c[8],  c[9]);
    unsigned wb = pk_bf16(c[10], c[11]);
    unsigned wc = pk_bf16(c[12], c[13]);
    unsigned wd = pk_bf16(c[14], c[15]);
    swap32(wa, wc); swap32(wb, wd);
    b1[0]=wa; b1[1]=wb; b1[2]=wc; b1[3]=wd;
  }
}

#define MFMA(a,b,c) __builtin_amdgcn_mfma_f32_32x32x16_bf16((a),(b),(c),0,0,0)

// Stage one layer's weights (bf16, ext rows for t/bias folding) into LDS, lane-ordered A-tiles.
__device__ void prep_weights(char* lds, int layer,
    const float* fW1, const float* fb1, const float* fW2, const float* fb2,
    const float* fW3, const float* fb3, const float* gW1, const float* gb1,
    const float* gW2, const float* gb2, const float* gW3, const float* gb3)
{
  const float* fW1l = fW1 + layer*34*128;
  const float* fb1l = fb1 + layer*128;
  const float* fW2l = fW2 + layer*128*128;
  const float* fb2l = fb2 + layer*128;
  const float* fW3l = fW3 + layer*128*32;
  const float* fb3l = fb3 + layer*32;
  const float* gW1l = gW1 + layer*2*128;
  const float* gb1l = gb1 + layer*128;
  const float* gW2l = gW2 + layer*128*128;
  const float* gb2l = gb2 + layer*128;
  const float* gW3l = gW3 + layer*128;
  const float* gb3l = gb3 + layer;

  for (int idx = threadIdx.x; idx < LDS_TILES*64; idx += WGSIZE){
    int tile = idx >> 6;
    int lam  = idx & 63;
    int r    = lam & 31;
    int ch   = lam >> 5;
    int mat, m, ks;
    if (tile < 12)      { mat=0; m=tile/3;        ks=tile%3; }
    else if (tile < 48) { mat=1; m=(tile-12)/9;   ks=(tile-12)%9; }
    else if (tile < 57) { mat=2; m=0;             ks=tile-48; }
    else if (tile < 61) { mat=3; m=tile-57;       ks=0; }
    else if (tile < 97) { mat=4; m=(tile-61)/9;   ks=(tile-61)%9; }
    else                { mat=5; m=0;             ks=tile-97; }
    int row = 32*m + r;
    int k0 = ks*16 + 8*ch;
    unsigned short hv[8];
    #pragma unroll
    for (int e=0;e<8;e++){
      int k = k0 + e;
      float v = 0.0f;
      switch(mat){
        case 0: // f W1 ext: k<32 -> x_k (row k+1), 32 -> z (row 33), 33 -> t (row 0), 34 -> b1
          if (k < 32)       v = fW1l[(k+1)*128 + row];
          else if (k == 32) v = fW1l[33*128 + row];
          else if (k == 33) v = fW1l[row];
          else if (k == 34) v = fb1l[row];
          break;
        case 1:
          if (k < 128)      v = fW2l[k*128 + row];
          else if (k==128)  v = fb2l[row];
          break;
        case 2:
          if (k < 128)      v = fW3l[k*32 + row];
          else if (k==128)  v = fb3l[row];
          break;
        case 3: // g W1 ext: k0 -> z (gW1 row1), k1 -> t (gW1 row0), k2 -> b1g
          if (k == 0)       v = gW1l[128 + row];
          else if (k == 1)  v = gW1l[row];
          else if (k == 2)  v = gb1l[row];
          break;
        case 4:
          if (k < 128)      v = gW2l[k*128 + row];
          else if (k==128)  v = gb2l[row];
          break;
        case 5:
          if (row == 0){
            if (k < 128)     v = gW3l[k];
            else if (k==128) v = gb3l[0];
          }
          break;
      }
      hv[e] = f2bf(v);
    }
    uint4 val;
    val.x = (unsigned)hv[0] | ((unsigned)hv[1]<<16);
    val.y = (unsigned)hv[2] | ((unsigned)hv[3]<<16);
    val.z = (unsigned)hv[4] | ((unsigned)hv[5]<<16);
    val.w = (unsigned)hv[6] | ((unsigned)hv[7]<<16);
    *reinterpret_cast<uint4*>(lds + idx*16) = val;
  }
}

// One odefunc eval: input y (x in C-layout regs, z scalar), output kx (C-layout), kz.
__device__ __forceinline__ void evalF(const char* lds, int lane, float tcur,
    const float* yx, float yz, float* kx, float& kz)
{
  const bool lo = (lane < 32);
  unsigned by0[4], by1[4];
  cvt2arr(yx, by0, by1);                       // feature ksteps 0,1 = x dims 0..31
  unsigned bz2[4];                              // kstep 2 = [z, t, 1, 0...] (g0 lanes)
  bz2[0] = lo ? pk_bf16(yz, tcur) : 0u;
  bz2[1] = lo ? 0x3F80u : 0u;
  bz2[2] = 0u; bz2[3] = 0u;
  unsigned bon[4];                              // ones-row kstep (bias)
  bon[0] = lo ? 0x3F80u : 0u; bon[1]=0u; bon[2]=0u; bon[3]=0u;

  bf16x8 vy0 = frag_of(by0), vy1 = frag_of(by1), vy2 = frag_of(bz2), von = frag_of(bon);

  f32x16 C[4];
  unsigned bh1[8][4];
  unsigned bh2[8][4];
  float tmp[16];

  // ---------- f net ----------
  #pragma unroll
  for (int m=0;m<4;m++) C[m] = zero16();
  #pragma unroll
  for (int ks=0;ks<3;ks++){
    bf16x8 vb = (ks==0) ? vy0 : (ks==1) ? vy1 : vy2;
    #pragma unroll
    for (int m=0;m<4;m++)
      C[m] = MFMA(ldA(lds, T_W1F + m*3 + ks, lane), vb, C[m]);
  }
  #pragma unroll
  for (int m=0;m<4;m++){
    #pragma unroll
    for (int i=0;i<16;i++) tmp[i] = fast_tanh(C[m][i]);
    cvt2arr(tmp, bh1[2*m], bh1[2*m+1]);
  }

  #pragma unroll
  for (int m=0;m<4;m++) C[m] = zero16();
  #pragma unroll
  for (int ks=0;ks<9;ks++){
    bf16x8 vb = (ks<8) ? frag_of(bh1[ks]) : von;
    #pragma unroll
    for (int m=0;m<4;m++)
      C[m] = MFMA(ldA(lds, T_W2F + m*9 + ks, lane), vb, C[m]);
  }
  #pragma unroll
  for (int m=0;m<4;m++){
    #pragma unroll
    for (int i=0;i<16;i++) tmp[i] = fast_tanh(C[m][i]);
    cvt2arr(tmp, bh2[2*m], bh2[2*m+1]);
  }

  {
    f32x16 Da = zero16(), Db = zero16();
    #pragma unroll
    for (int ks=0;ks<4;ks++){
      Da = MFMA(ldA(lds, T_W3F + 2*ks,   lane), frag_of(bh2[2*ks]),   Da);
      Db = MFMA(ldA(lds, T_W3F + 2*ks+1, lane), frag_of(bh2[2*ks+1]), Db);
    }
    Da = MFMA(ldA(lds, T_W3F + 8, lane), von, Da);
    #pragma unroll
    for (int i=0;i<16;i++) kx[i] = Da[i] + Db[i];
  }

  // ---------- g net ----------
  #pragma unroll
  for (int m=0;m<4;m++){
    f32x16 Cg = MFMA(ldA(lds, T_W1G + m, lane), vy2, zero16());
    #pragma unroll
    for (int i=0;i<16;i++) tmp[i] = fast_tanh(Cg[i]);
    cvt2arr(tmp, bh1[2*m], bh1[2*m+1]);
  }

  #pragma unroll
  for (int m=0;m<4;m++) C[m] = zero16();
  #pragma unroll
  for (int ks=0;ks<9;ks++){
    bf16x8 vb = (ks<8) ? frag_of(bh1[ks]) : von;
    #pragma unroll
    for (int m=0;m<4;m++)
      C[m] = MFMA(ldA(lds, T_W2G + m*9 + ks, lane), vb, C[m]);
  }
  #pragma unroll
  for (int m=0;m<4;m++){
    #pragma unroll
    for (int i=0;i<16;i++) tmp[i] = fast_tanh(C[m][i]);
    cvt2arr(tmp, bh2[2*m], bh2[2*m+1]);
  }

  {
    f32x16 Da = zero16(), Db = zero16();
    #pragma unroll
    for (int ks=0;ks<4;ks++){
      Da = MFMA(ldA(lds, T_W3G + 2*ks,   lane), frag_of(bh2[2*ks]),   Da);
      Db = MFMA(ldA(lds, T_W3G + 2*ks+1, lane), frag_of(bh2[2*ks+1]), Db);
    }
    Da = MFMA(ldA(lds, T_W3G + 8, lane), von, Da);
    float dz0 = Da[0] + Db[0];                 // row 0 valid on g0 lanes
    unsigned du = __float_as_uint(dz0);
    unsigned su = du;
    swap32(du, su);                             // broadcast g0 half -> all lanes
    kz = __uint_as_float(du);
  }
}

extern "C" __global__ void __launch_bounds__(WGSIZE, 2)
node_fused(const float* __restrict__ w, const float* __restrict__ tin,
    const float* __restrict__ fW1, const float* __restrict__ fb1,
    const float* __restrict__ fW2, const float* __restrict__ fb2,
    const float* __restrict__ fW3, const float* __restrict__ fb3,
    const float* __restrict__ gW1, const float* __restrict__ gb1,
    const float* __restrict__ gW2, const float* __restrict__ gb2,
    const float* __restrict__ gW3, const float* __restrict__ gb3,
    float* __restrict__ out)
{
  extern __shared__ __align__(16) char lds_mem[];
  const int tid  = threadIdx.x;
  const int lane = tid & 63;
  const int wv   = tid >> 6;
  const int g    = lane >> 5;
  const int col  = lane & 31;
  const int pt   = blockIdx.x*PTS_PER_BLOCK + wv*32 + col;

  // state x in C-frag layout: reg r <-> dim d = (r&3) + 8*(r>>2) + 4*g
  float sx[16];
  #pragma unroll
  for (int q=0;q<4;q++){
    float4 v = *reinterpret_cast<const float4*>(w + (size_t)pt*32 + 8*q + 4*g);
    sx[4*q+0]=v.x; sx[4*q+1]=v.y; sx[4*q+2]=v.z; sx[4*q+3]=v.w;
  }
  float sz = tin[pt];

  const float dt  = 1.0f/16.0f;
  const float hdt = 0.5f*dt;
  const float w6  = dt/6.0f;

  #pragma unroll 1
  for (int layer=0; layer<2; layer++){
    __syncthreads();
    prep_weights(lds_mem, layer, fW1, fb1, fW2, fb2, fW3, fb3,
                 gW1, gb1, gW2, gb2, gW3, gb3);
    __syncthreads();

    #pragma unroll 1
    for (int step=0; step<16; step++){
      float t0 = (float)step * dt;
      float kx[16], yx[16], ax[16];
      float kz, yz, az;

      evalF(lds_mem, lane, t0, sx, sz, kx, kz);
      #pragma unroll
      for (int i=0;i<16;i++){ ax[i]=kx[i]; yx[i]=sx[i]+hdt*kx[i]; }
      az = kz; yz = sz + hdt*kz;

      evalF(lds_mem, lane, t0+hdt, yx, yz, kx, kz);
      #pragma unroll
      for (int i=0;i<16;i++){ ax[i]+=2.0f*kx[i]; yx[i]=sx[i]+hdt*kx[i]; }
      az += 2.0f*kz; yz = sz + hdt*kz;

      evalF(lds_mem, lane, t0+hdt, yx, yz, kx, kz);
      #pragma unroll
      for (int i=0;i<16;i++){ ax[i]+=2.0f*kx[i]; yx[i]=sx[i]+dt*kx[i]; }
      az += 2.0f*kz; yz = sz + dt*kz;

      evalF(lds_mem, lane, t0+dt, yx, yz, kx, kz);
      #pragma unroll
      for (int i=0;i<16;i++) sx[i] += w6*(ax[i]+kx[i]);
      sz += w6*(az+kz);
    }
  }

  #pragma unroll
  for (int q=0;q<4;q++){
    float4 v;
    v.x=sx[4*q+0]; v.y=sx[4*q+1]; v.z=sx[4*q+2]; v.w=sx[4*q+3];
    *reinterpret_cast<float4*>(out + (size_t)pt*32 + 8*q + 4*g) = v;
  }
}

extern "C" void kernel_launch(void* const* d_in, const int* in_sizes, int n_in,
                              void* d_out, int out_size, void* d_ws, size_t ws_size,
                              hipStream_t stream) {
  const float* w   = (const float*)d_in[0];
  const float* t   = (const float*)d_in[1];
  const float* fW1 = (const float*)d_in[2];
  const float* fb1 = (const float*)d_in[3];
  const float* fW2 = (const float*)d_in[4];
  const float* fb2 = (const float*)d_in[5];
  const float* fW3 = (const float*)d_in[6];
  const float* fb3 = (const float*)d_in[7];
  const float* gW1 = (const float*)d_in[8];
  const float* gb1 = (const float*)d_in[9];
  const float* gW2 = (const float*)d_in[10];
  const float* gb2 = (const float*)d_in[11];
  const float* gW3 = (const float*)d_in[12];
  const float* gb3 = (const float*)d_in[13];
  float* out = (float*)d_out;

  hipFuncSetAttribute(reinterpret_cast<const void*>(node_fused),
                      hipFuncAttributeMaxDynamicSharedMemorySize, LDS_BYTES);
  node_fused<<<NBLOCKS, WGSIZE, LDS_BYTES, stream>>>(
      w, t, fW1, fb1, fW2, fb2, fW3, fb3, gW1, gb1, gW2, gb2, gW3, gb3, out);
}

// Round 2
// 10346.307 us; speedup vs baseline: 3.0825x; 3.0825x over previous
//
#include <hip/hip_runtime.h>

#define WGSIZE 512
#define PTS_PER_BLOCK 256           // 8 waves * 32 points
#define NPTS (512*1024)
#define NBLOCKS (NPTS/PTS_PER_BLOCK) // 2048

typedef __bf16 bf16x8 __attribute__((ext_vector_type(8)));
typedef float f32x16 __attribute__((ext_vector_type(16)));

// LDS weight tile map (1KB per 32x16 bf16 A-tile, lane-ordered)
#define T_W1F 0    // 4 rowtiles x 3 ksteps  (K=48: [x32, z, t, 1, pad])
#define T_W2F 12   // 4 x 9                  (K=144: [h128, 1, pad])
#define T_W3F 48   // 1 x 9
#define T_W1G 57   // 4 x 1                  (K=16: [z, t, 1, pad])
#define T_W2G 61   // 4 x 9
#define T_W3G 97   // 1 x 9
#define LDS_TILES 106
#define LDS_BYTES (LDS_TILES*1024)

__device__ __forceinline__ unsigned pk_bf16(float a, float b){
  unsigned r;
  asm("v_cvt_pk_bf16_f32 %0, %1, %2" : "=v"(r) : "v"(a), "v"(b));
  return r;
}

__device__ __forceinline__ void swap32(unsigned &d, unsigned &s){
  auto r = __builtin_amdgcn_permlane32_swap((int)d, (int)s, false, false);
  d = (unsigned)r[0];
  s = (unsigned)r[1];
}

__device__ __forceinline__ float fast_tanh(float x){
  float e = __expf(2.0f*x);                       // overflow -> inf -> tanh=1 ok
  return 1.0f - 2.0f*__builtin_amdgcn_rcpf(e + 1.0f);
}

__device__ __forceinline__ unsigned short f2bf(float f){ // RNE f32->bf16
  unsigned u = __float_as_uint(f);
  u += 0x7fffu + ((u>>16)&1u);
  return (unsigned short)(u>>16);
}

__device__ __forceinline__ bf16x8 frag_of(const unsigned wv[4]){
  union { uint4 u; bf16x8 b; } x;
  x.u.x = wv[0]; x.u.y = wv[1]; x.u.z = wv[2]; x.u.w = wv[3];
  return x.b;
}

__device__ __forceinline__ bf16x8 ldA(const char* lds, int tile, int lane){
  union { uint4 u; bf16x8 b; } x;
  x.u = *reinterpret_cast<const uint4*>(lds + tile*1024 + lane*16);
  return x.b;
}

__device__ __forceinline__ f32x16 zero16(){
  f32x16 z;
  #pragma unroll
  for (int i=0;i<16;i++) z[i]=0.0f;
  return z;
}

// C-frag (16 f32) -> two B-frag ksteps (bf16), via pk+permlane swaps.
__device__ __forceinline__ void cvt2arr(const float* c, unsigned* b0, unsigned* b1){
  {
    unsigned wa = pk_bf16(c[0], c[1]);
    unsigned wb = pk_bf16(c[2], c[3]);
    unsigned wc = pk_bf16(c[4], c[5]);
    unsigned wd = pk_bf16(c[6], c[7]);
    swap32(wa, wc); swap32(wb, wd);
    b0[0]=wa; b0[1]=wb; b0[2]=wc; b0[3]=wd;
  }
  {
    unsigned wa = pk_bf16(c[8],  c[9]);
    unsigned wb = pk_bf16(c[10], c[11]);
    unsigned wc = pk_bf16(c[12], c[13]);
    unsigned wd = pk_bf16(c[14], c[15]);
    swap32(wa, wc); swap32(wb, wd);
    b1[0]=wa; b1[1]=wb; b1[2]=wc; b1[3]=wd;
  }
}

// tanh of a C-frag then convert to two packed B-frag ksteps.
__device__ __forceinline__ void cvt2arr_tanh(const f32x16& c, unsigned* b0, unsigned* b1){
  float t[16];
  #pragma unroll
  for (int i=0;i<16;i++) t[i] = fast_tanh(c[i]);
  cvt2arr(t, b0, b1);
}

#define MFMA(a,b,c) __builtin_amdgcn_mfma_f32_32x32x16_bf16((a),(b),(c),0,0,0)

// Stage one layer's weights (bf16, ext rows for t/bias folding) into LDS, lane-ordered A-tiles.
__device__ void prep_weights(char* lds, int layer,
    const float* fW1, const float* fb1, const float* fW2, const float* fb2,
    const float* fW3, const float* fb3, const float* gW1, const float* gb1,
    const float* gW2, const float* gb2, const float* gW3, const float* gb3)
{
  const float* fW1l = fW1 + layer*34*128;
  const float* fb1l = fb1 + layer*128;
  const float* fW2l = fW2 + layer*128*128;
  const float* fb2l = fb2 + layer*128;
  const float* fW3l = fW3 + layer*128*32;
  const float* fb3l = fb3 + layer*32;
  const float* gW1l = gW1 + layer*2*128;
  const float* gb1l = gb1 + layer*128;
  const float* gW2l = gW2 + layer*128*128;
  const float* gb2l = gb2 + layer*128;
  const float* gW3l = gW3 + layer*128;
  const float* gb3l = gb3 + layer;

  for (int idx = threadIdx.x; idx < LDS_TILES*64; idx += WGSIZE){
    int tile = idx >> 6;
    int lam  = idx & 63;
    int r    = lam & 31;
    int ch   = lam >> 5;
    int mat, m, ks;
    if (tile < 12)      { mat=0; m=tile/3;        ks=tile%3; }
    else if (tile < 48) { mat=1; m=(tile-12)/9;   ks=(tile-12)%9; }
    else if (tile < 57) { mat=2; m=0;             ks=tile-48; }
    else if (tile < 61) { mat=3; m=tile-57;       ks=0; }
    else if (tile < 97) { mat=4; m=(tile-61)/9;   ks=(tile-61)%9; }
    else                { mat=5; m=0;             ks=tile-97; }
    int row = 32*m + r;
    int k0 = ks*16 + 8*ch;
    unsigned short hv[8];
    #pragma unroll
    for (int e=0;e<8;e++){
      int k = k0 + e;
      float v = 0.0f;
      switch(mat){
        case 0: // f W1 ext: k<32 -> x_k (row k+1), 32 -> z (row 33), 33 -> t (row 0), 34 -> b1
          if (k < 32)       v = fW1l[(k+1)*128 + row];
          else if (k == 32) v = fW1l[33*128 + row];
          else if (k == 33) v = fW1l[row];
          else if (k == 34) v = fb1l[row];
          break;
        case 1:
          if (k < 128)      v = fW2l[k*128 + row];
          else if (k==128)  v = fb2l[row];
          break;
        case 2:
          if (k < 128)      v = fW3l[k*32 + row];
          else if (k==128)  v = fb3l[row];
          break;
        case 3: // g W1 ext: k0 -> z (gW1 row1), k1 -> t (gW1 row0), k2 -> b1g
          if (k == 0)       v = gW1l[128 + row];
          else if (k == 1)  v = gW1l[row];
          else if (k == 2)  v = gb1l[row];
          break;
        case 4:
          if (k < 128)      v = gW2l[k*128 + row];
          else if (k==128)  v = gb2l[row];
          break;
        case 5:
          if (row == 0){
            if (k < 128)     v = gW3l[k];
            else if (k==128) v = gb3l[0];
          }
          break;
      }
      hv[e] = f2bf(v);
    }
    uint4 val;
    val.x = (unsigned)hv[0] | ((unsigned)hv[1]<<16);
    val.y = (unsigned)hv[2] | ((unsigned)hv[3]<<16);
    val.z = (unsigned)hv[4] | ((unsigned)hv[5]<<16);
    val.w = (unsigned)hv[6] | ((unsigned)hv[7]<<16);
    *reinterpret_cast<uint4*>(lds + idx*16) = val;
  }
}

// One odefunc eval, register-lean (m-outer, single running D accumulator).
// xio: input y_x (C-layout), overwritten with k_x. yz in, kz out.
__device__ __forceinline__ void evalF(const char* lds, int lane, float tcur,
    float* xio, float yz, float& kz)
{
  const bool lo = (lane < 32);
  unsigned by0[4], by1[4];
  cvt2arr(xio, by0, by1);                       // feature ksteps 0,1 = x dims 0..31
  unsigned bz2[4];                              // kstep 2 = [z, t, 1, 0...]
  bz2[0] = lo ? pk_bf16(yz, tcur) : 0u;
  bz2[1] = lo ? 0x3F80u : 0u;
  bz2[2] = 0u; bz2[3] = 0u;
  unsigned bon[4];                              // ones-row kstep (bias)
  bon[0] = lo ? 0x3F80u : 0u; bon[1]=0u; bon[2]=0u; bon[3]=0u;

  bf16x8 vy2 = frag_of(bz2), von = frag_of(bon);

  unsigned bh1[8][4];

  // ---------- f net ----------
  {
    bf16x8 vy0 = frag_of(by0), vy1 = frag_of(by1);
    #pragma unroll
    for (int m=0;m<4;m++){
      f32x16 C = MFMA(ldA(lds, T_W1F + m*3 + 0, lane), vy0, zero16());
      C = MFMA(ldA(lds, T_W1F + m*3 + 1, lane), vy1, C);
      C = MFMA(ldA(lds, T_W1F + m*3 + 2, lane), vy2, C);
      cvt2arr_tanh(C, bh1[2*m], bh1[2*m+1]);
    }
  }
  {
    f32x16 D = zero16();
    #pragma unroll
    for (int m=0;m<4;m++){
      f32x16 C = zero16();
      #pragma unroll
      for (int ks=0;ks<8;ks++)
        C = MFMA(ldA(lds, T_W2F + m*9 + ks, lane), frag_of(bh1[ks]), C);
      C = MFMA(ldA(lds, T_W2F + m*9 + 8, lane), von, C);
      unsigned b2a[4], b2b[4];
      cvt2arr_tanh(C, b2a, b2b);
      D = MFMA(ldA(lds, T_W3F + 2*m,   lane), frag_of(b2a), D);
      D = MFMA(ldA(lds, T_W3F + 2*m+1, lane), frag_of(b2b), D);
    }
    D = MFMA(ldA(lds, T_W3F + 8, lane), von, D);
    #pragma unroll
    for (int i=0;i<16;i++) xio[i] = D[i];
  }

  // ---------- g net ----------
  #pragma unroll
  for (int m=0;m<4;m++){
    f32x16 C = MFMA(ldA(lds, T_W1G + m, lane), vy2, zero16());
    cvt2arr_tanh(C, bh1[2*m], bh1[2*m+1]);
  }
  {
    f32x16 D = zero16();
    #pragma unroll
    for (int m=0;m<4;m++){
      f32x16 C = zero16();
      #pragma unroll
      for (int ks=0;ks<8;ks++)
        C = MFMA(ldA(lds, T_W2G + m*9 + ks, lane), frag_of(bh1[ks]), C);
      C = MFMA(ldA(lds, T_W2G + m*9 + 8, lane), von, C);
      unsigned b2a[4], b2b[4];
      cvt2arr_tanh(C, b2a, b2b);
      D = MFMA(ldA(lds, T_W3G + 2*m,   lane), frag_of(b2a), D);
      D = MFMA(ldA(lds, T_W3G + 2*m+1, lane), frag_of(b2b), D);
    }
    D = MFMA(ldA(lds, T_W3G + 8, lane), von, D);
    float dz0 = D[0];                           // row 0 valid on lanes<32
    unsigned du = __float_as_uint(dz0);
    unsigned su = du;
    swap32(du, su);                             // broadcast lo half -> all lanes
    kz = __uint_as_float(du);
  }
}

extern "C" __global__ void __launch_bounds__(WGSIZE, 2)
node_fused(const float* __restrict__ w, const float* __restrict__ tin,
    const float* __restrict__ fW1, const float* __restrict__ fb1,
    const float* __restrict__ fW2, const float* __restrict__ fb2,
    const float* __restrict__ fW3, const float* __restrict__ fb3,
    const float* __restrict__ gW1, const float* __restrict__ gb1,
    const float* __restrict__ gW2, const float* __restrict__ gb2,
    const float* __restrict__ gW3, const float* __restrict__ gb3,
    float* __restrict__ out)
{
  extern __shared__ __align__(16) char lds_mem[];
  const int tid  = threadIdx.x;
  const int lane = tid & 63;
  const int wv   = tid >> 6;
  const int g    = lane >> 5;
  const int col  = lane & 31;
  const int pt   = blockIdx.x*PTS_PER_BLOCK + wv*32 + col;

  // state x in C-frag layout: reg r <-> dim d = (r&3) + 8*(r>>2) + 4*g
  float sx[16];
  #pragma unroll
  for (int q=0;q<4;q++){
    float4 v = *reinterpret_cast<const float4*>(w + (size_t)pt*32 + 8*q + 4*g);
    sx[4*q+0]=v.x; sx[4*q+1]=v.y; sx[4*q+2]=v.z; sx[4*q+3]=v.w;
  }
  float sz = tin[pt];

  const float dt  = 1.0f/16.0f;
  const float hdt = 0.5f*dt;
  const float w6  = dt/6.0f;

  #pragma unroll 1
  for (int layer=0; layer<2; layer++){
    __syncthreads();
    prep_weights(lds_mem, layer, fW1, fb1, fW2, fb2, fW3, fb3,
                 gW1, gb1, gW2, gb2, gW3, gb3);
    __syncthreads();

    #pragma unroll 1
    for (int step=0; step<16; step++){
      float t0 = (float)step * dt;
      float yx[16], ax[16];
      float yz, az;
      #pragma unroll
      for (int i=0;i<16;i++){ yx[i]=sx[i]; ax[i]=0.0f; }
      yz = sz; az = 0.0f;

      #pragma unroll 1
      for (int s=0;s<4;s++){
        float toff = (s==0) ? 0.0f : (s==3) ? dt : hdt;   // wave-uniform (SALU)
        float wgt  = (s==0 || s==3) ? w6 : 2.0f*w6;
        float stp  = (s==2) ? dt : hdt;
        float kz;
        evalF(lds_mem, lane, t0+toff, yx, yz, kz);        // yx now holds k_x
        #pragma unroll
        for (int i=0;i<16;i++){
          float k = yx[i];
          ax[i] += wgt*k;
          yx[i]  = sx[i] + stp*k;
        }
        az += wgt*kz;
        yz  = sz + stp*kz;
      }
      #pragma unroll
      for (int i=0;i<16;i++) sx[i] += ax[i];
      sz += az;
    }
  }

  #pragma unroll
  for (int q=0;q<4;q++){
    float4 v;
    v.x=sx[4*q+0]; v.y=sx[4*q+1]; v.z=sx[4*q+2]; v.w=sx[4*q+3];
    *reinterpret_cast<float4*>(out + (size_t)pt*32 + 8*q + 4*g) = v;
  }
}

extern "C" void kernel_launch(void* const* d_in, const int* in_sizes, int n_in,
                              void* d_out, int out_size, void* d_ws, size_t ws_size,
                              hipStream_t stream) {
  const float* w   = (const float*)d_in[0];
  const float* t   = (const float*)d_in[1];
  const float* fW1 = (const float*)d_in[2];
  const float* fb1 = (const float*)d_in[3];
  const float* fW2 = (const float*)d_in[4];
  const float* fb2 = (const float*)d_in[5];
  const float* fW3 = (const float*)d_in[6];
  const float* fb3 = (const float*)d_in[7];
  const float* gW1 = (const float*)d_in[8];
  const float* gb1 = (const float*)d_in[9];
  const float* gW2 = (const float*)d_in[10];
  const float* gb2 = (const float*)d_in[11];
  const float* gW3 = (const float*)d_in[12];
  const float* gb3 = (const float*)d_in[13];
  float* out = (float*)d_out;

  hipFuncSetAttribute(reinterpret_cast<const void*>(node_fused),
                      hipFuncAttributeMaxDynamicSharedMemorySize, LDS_BYTES);
  node_fused<<<NBLOCKS, WGSIZE, LDS_BYTES, stream>>>(
      w, t, fW1, fb1, fW2, fb2, fW3, fb3, gW1, gb1, gW2, gb2, gW3, gb3, out);
}